// Round 14
// baseline (122.209 us; speedup 1.0000x reference)
//
#include <hip/hip_runtime.h>
#include <hip/hip_bf16.h>
#include <stdint.h>

#define B_   64
#define T_   8192
#define D_   128
#define L_   64
#define SUB  64        // tokens per record slot (one wave)
#define TIL  32        // tokens per micro-tile (one conv/GEMM pass)
#define NSC  128       // record slots per batch (T/SUB)
#define NXB  32        // blocks per batch: 32 blk x 4 waves = 128 wave-slots
#define XSF  136       // padded LDS row stride (bf16 elems), HW-verified

typedef float f32x4 __attribute__((ext_vector_type(4)));
typedef short s16x8 __attribute__((ext_vector_type(8)));
typedef short s16x4 __attribute__((ext_vector_type(4)));

__device__ __forceinline__ uint16_t f2bf(float f) {
  __hip_bfloat16 h = __float2bfloat16(f);          // HW RNE
  return *(uint16_t*)&h;
}
__device__ __forceinline__ float bfbits2f(uint16_t h) {
  union { uint32_t u; float f; } c; c.u = ((uint32_t)h) << 16; return c.f;
}
template <int CTRL>
__device__ __forceinline__ float dpp_add(float v) {
  int t = __builtin_amdgcn_update_dpp(0, __builtin_bit_cast(int, v), CTRL, 0xf, 0xf, false);
  return v + __builtin_bit_cast(float, t);
}
template <int CTRL>
__device__ __forceinline__ float dpp_max(float v) {
  int t = __builtin_amdgcn_update_dpp(0, __builtin_bit_cast(int, v), CTRL, 0xf, 0xf, false);
  return fmaxf(v, __builtin_bit_cast(float, t));
}
__device__ __forceinline__ float rdlane(float v, int lane) {
  return __builtin_bit_cast(float, __builtin_amdgcn_readlane(__builtin_bit_cast(int, v), lane));
}

// ---------------------------------------------------------------------------
// prep: blocks 0..15 pack W_k/W_q into bf16 hi/lo MFMA B-fragment order;
// block 16 normalizes lengths (int32 OR int64).  (HW-verified r2-r13)
// B-frag: n = w*16 + (lane&15); k = kk*32 + 4*(lane>>4) + (j&3) + 16*(j>>2)
// frag id = mat*32 + term*16 + w*4 + kk.
// ---------------------------------------------------------------------------
__global__ void prep(const float* __restrict__ key_w,
                     const float* __restrict__ query_w,
                     const void* __restrict__ lengths_raw,
                     uint16_t* __restrict__ wfrag,
                     int* __restrict__ lens) {
  if (blockIdx.x == 16) {
    const int tid = threadIdx.x;
    if (tid >= 64) return;
    const int* s32 = (const int*)lengths_raw;
    bool odd_zero = (tid < 32) ? (s32[2 * tid + 1] == 0) : true;
    bool is64 = __all(odd_zero);
    int v;
    if (is64) v = (int)((const long long*)lengths_raw)[tid];
    else      v = s32[tid];
    lens[tid] = v;
    return;
  }
  int gid  = blockIdx.x * 256 + threadIdx.x;
  int lane = gid & 63;
  int frag = gid >> 6;
  int kk   = frag & 3;
  int w    = (frag >> 2) & 3;
  int term = (frag >> 4) & 1;
  int mat  = frag >> 5;
  const float* src = mat ? query_w : key_w;
  int n = w * 16 + (lane & 15);
  int g = lane >> 4;
  uint16_t o[8];
#pragma unroll
  for (int j = 0; j < 8; ++j) {
    int k = kk * 32 + g * 4 + (j & 3) + 16 * (j >> 2);
    float v = src[k * L_ + n];
    uint16_t hi = f2bf(v);
    if (term == 0) o[j] = hi;
    else           o[j] = f2bf(v - bfbits2f(hi));
  }
  uint16_t* dst = wfrag + (size_t)frag * 512 + lane * 8;
#pragma unroll
  for (int j = 0; j < 8; ++j) dst[j] = o[j];
}

// ---------------------------------------------------------------------------
// attn_partial (r14): ONE WAVE per 64-token record slot; ZERO barriers.
// Each wave: two 32-token micro-tiles, online-softmax merged. Private LDS
// slice per wave; wave-local ds_write->ds_read needs only lgkmcnt (compiler-
// inserted). 4 waves/block fully independent -> phases de-correlate across
// the 8 resident waves/CU, turning sum-of-phases into max-of-pipes.
// ---------------------------------------------------------------------------
__global__ __launch_bounds__(256, 2) void attn_partial(
    const float* __restrict__ seq, const int* __restrict__ lens,
    const uint16_t* __restrict__ wfrag,
    float2* __restrict__ msbuf, float* __restrict__ accbuf) {
  const int b    = blockIdx.y;
  const int xb   = blockIdx.x;
  const int tid  = threadIdx.x;
  const int lane = tid & 63;
  const int wv   = tid >> 6;
  const int len  = lens[b];

  const int s = xb * 4 + wv;                 // record slot 0..127
  if (s * SUB >= len) return;                // invalid slot: no record (combine is vb-bounded)

  __shared__ uint16_t XFhi[4][TIL * XSF];
  __shared__ uint16_t XFlo[4][TIL * XSF];
  __shared__ float    lgt [4][TIL];

  uint16_t* XH = XFhi[wv];
  uint16_t* XL = XFlo[wv];
  float*    LG = lgt[wv];

  const int q32  = lane & 31;
  const int half = lane >> 5;
  const int c    = lane & 15;
  const int g2   = lane >> 4;
  // conv permutation (HW-verified r3-r13): d0=(q32)*4 -> frag-contiguous pos
  const int p0 = ((q32 >> 3) & 3) * 32 + (q32 & 3) * 8 + ((q32 >> 2) & 1) * 4;

  float M = -1e30f, S = 0.f;
  f32x4 pacc = (f32x4){0.f, 0.f, 0.f, 0.f};

  const int remain = len - s * SUB;          // >= 1
  const int ntile = (remain > TIL) ? 2 : 1;

  for (int t = 0; t < ntile; ++t) {
    const int tstart = s * SUB + t * TIL;
    const float* sp = seq + ((size_t)b * T_ + tstart) * D_;

    // ---- load 32x128 fp32 tile: 16 f32x4 per lane ----
    f32x4 v[16];
#pragma unroll
    for (int j = 0; j < 16; ++j) v[j] = ((const f32x4*)sp)[lane + 64 * j];

    // ---- convert fp32 -> bf16 hi/lo into this wave's frag-contiguous tile ----
#pragma unroll
    for (int j = 0; j < 16; ++j) {
      const int tok = 2 * j + half;          // row in tile 0..31
      f32x4 x = v[j];
      uint16_t h0 = f2bf(x[0]), h1 = f2bf(x[1]), h2 = f2bf(x[2]), h3 = f2bf(x[3]);
      *(s16x4*)(&XH[tok * XSF + p0]) = (s16x4){(short)h0, (short)h1, (short)h2, (short)h3};
      uint16_t l0 = f2bf(x[0] - bfbits2f(h0));
      uint16_t l1 = f2bf(x[1] - bfbits2f(h1));
      uint16_t l2 = f2bf(x[2] - bfbits2f(h2));
      uint16_t l3 = f2bf(x[3] - bfbits2f(h3));
      *(s16x4*)(&XL[tok * XSF + p0]) = (s16x4){(short)l0, (short)l1, (short)l2, (short)l3};
    }
    // (no barrier: wave-local LDS; compiler inserts lgkmcnt before reads)

    // ---- K = X Wk, Q = X Wq over all 4 L-tiles (XhWh + XhWl + XlWh) ----
    f32x4 kacc[2][4], qacc[2][4];
#pragma unroll
    for (int m = 0; m < 2; ++m)
#pragma unroll
      for (int w = 0; w < 4; ++w) {
        kacc[m][w] = (f32x4){0.f, 0.f, 0.f, 0.f};
        qacc[m][w] = (f32x4){0.f, 0.f, 0.f, 0.f};
      }
#pragma unroll
    for (int kk = 0; kk < 4; ++kk) {
      const int eo0 = (0 * 16 + c) * XSF + kk * 32 + g2 * 8;
      const int eo1 = (1 * 16 + c) * XSF + kk * 32 + g2 * 8;
      s16x8 ah0 = *(const s16x8*)(&XH[eo0]);
      s16x8 ah1 = *(const s16x8*)(&XH[eo1]);
      s16x8 al0 = *(const s16x8*)(&XL[eo0]);
      s16x8 al1 = *(const s16x8*)(&XL[eo1]);
#pragma unroll
      for (int w = 0; w < 4; ++w) {
        const uint16_t* wf = wfrag;
        asm volatile("" : "+s"(wf));         // opaque: keep W loads in-loop (r13)
        s16x8 wkh = *(const s16x8*)(wf + (size_t)( 0 + w * 4 + kk) * 512 + lane * 8);
        s16x8 wkl = *(const s16x8*)(wf + (size_t)(16 + w * 4 + kk) * 512 + lane * 8);
        s16x8 wqh = *(const s16x8*)(wf + (size_t)(32 + w * 4 + kk) * 512 + lane * 8);
        s16x8 wql = *(const s16x8*)(wf + (size_t)(48 + w * 4 + kk) * 512 + lane * 8);
        kacc[0][w] = __builtin_amdgcn_mfma_f32_16x16x32_bf16(ah0, wkh, kacc[0][w], 0, 0, 0);
        kacc[0][w] = __builtin_amdgcn_mfma_f32_16x16x32_bf16(ah0, wkl, kacc[0][w], 0, 0, 0);
        kacc[0][w] = __builtin_amdgcn_mfma_f32_16x16x32_bf16(al0, wkh, kacc[0][w], 0, 0, 0);
        kacc[1][w] = __builtin_amdgcn_mfma_f32_16x16x32_bf16(ah1, wkh, kacc[1][w], 0, 0, 0);
        kacc[1][w] = __builtin_amdgcn_mfma_f32_16x16x32_bf16(ah1, wkl, kacc[1][w], 0, 0, 0);
        kacc[1][w] = __builtin_amdgcn_mfma_f32_16x16x32_bf16(al1, wkh, kacc[1][w], 0, 0, 0);
        qacc[0][w] = __builtin_amdgcn_mfma_f32_16x16x32_bf16(ah0, wqh, qacc[0][w], 0, 0, 0);
        qacc[0][w] = __builtin_amdgcn_mfma_f32_16x16x32_bf16(ah0, wql, qacc[0][w], 0, 0, 0);
        qacc[0][w] = __builtin_amdgcn_mfma_f32_16x16x32_bf16(al0, wqh, qacc[0][w], 0, 0, 0);
        qacc[1][w] = __builtin_amdgcn_mfma_f32_16x16x32_bf16(ah1, wqh, qacc[1][w], 0, 0, 0);
        qacc[1][w] = __builtin_amdgcn_mfma_f32_16x16x32_bf16(ah1, wql, qacc[1][w], 0, 0, 0);
        qacc[1][w] = __builtin_amdgcn_mfma_f32_16x16x32_bf16(al1, wqh, qacc[1][w], 0, 0, 0);
      }
    }

    // ---- logits: per (m,r) dot over L = Sum_w k*q, then DPP 16-lane reduce ----
#pragma unroll
    for (int m = 0; m < 2; ++m) {
#pragma unroll
      for (int r = 0; r < 4; ++r) {
        float val = kacc[m][0][r] * qacc[m][0][r] + kacc[m][1][r] * qacc[m][1][r]
                  + kacc[m][2][r] * qacc[m][2][r] + kacc[m][3][r] * qacc[m][3][r];
        val = dpp_add<0x121>(val); val = dpp_add<0x122>(val);
        val = dpp_add<0x124>(val); val = dpp_add<0x128>(val);
        if (c == 0) LG[m * 16 + g2 * 4 + r] = val;   // token = m*16+g2*4+r
      }
    }
    // (wave-local lgkmcnt ordering)
    float lg = LG[q32];
    lg = (tstart + q32 < len) ? lg : -1e30f;

    // ---- online softmax over this 32-token tile ----
    float mx = lg;
    mx = dpp_max<0x121>(mx); mx = dpp_max<0x122>(mx);
    mx = dpp_max<0x124>(mx); mx = dpp_max<0x128>(mx);
    mx = fmaxf(mx, __shfl_xor(mx, 16));
    const float mNew = fmaxf(M, mx);
    const float f  = __expf(M - mNew);
    const float wt = __expf(lg - mNew);
    float ss = wt;
    ss = dpp_add<0x121>(ss); ss = dpp_add<0x122>(ss);
    ss = dpp_add<0x124>(ss); ss = dpp_add<0x128>(ss);
    ss += __shfl_xor(ss, 16);
    S = S * f + ss;
    M = mNew;

    // ---- pool from fp32 registers; weights via readlane ----
    pacc *= f;
#pragma unroll
    for (int j = 0; j < 16; ++j) {
      float wa = rdlane(wt, 2 * j);          // token 2j   (lanes 0-31 hold it)
      float wb = rdlane(wt, 2 * j + 1);      // token 2j+1
      float w = half ? wb : wa;
#pragma unroll
      for (int e = 0; e < 4; ++e) pacc[e] += w * v[j][e];
    }
  }

  // ---- write record: halves hold even/odd tokens of the same d-range ----
#pragma unroll
  for (int e = 0; e < 4; ++e) pacc[e] += __shfl_xor(pacc[e], 32);
  if (lane < 32)
    *(f32x4*)(accbuf + ((size_t)(b * NSC + s)) * D_ + q32 * 4) = pacc;
  if (lane == 0) msbuf[b * NSC + s] = make_float2(M, S);
}

// ---------------------------------------------------------------------------
// combine: merge the vb valid records per batch, add bias (r9-verified:
// reads only i < vb; invalid slots never touched).
// ---------------------------------------------------------------------------
__global__ __launch_bounds__(256) void attn_combine(
    const float2* __restrict__ msbuf, const float* __restrict__ accbuf,
    const int* __restrict__ lens,
    const float* __restrict__ bias, float* __restrict__ out) {
  const int b = blockIdx.x;
  const int tid = threadIdx.x;
  const int vb = (lens[b] + SUB - 1) >> 6;       // valid records, >= 1
  __shared__ float red[4];
  __shared__ float wexp[NSC];
  __shared__ float halfsum[D_];

  float2 v = (tid < vb) ? msbuf[b * NSC + tid] : make_float2(-1e30f, 0.f);
  float m = v.x;
  m = fmaxf(m, __shfl_xor(m, 32)); m = fmaxf(m, __shfl_xor(m, 16));
  m = fmaxf(m, __shfl_xor(m, 8));  m = fmaxf(m, __shfl_xor(m, 4));
  m = fmaxf(m, __shfl_xor(m, 2));  m = fmaxf(m, __shfl_xor(m, 1));
  if ((tid & 63) == 0) red[tid >> 6] = m;
  __syncthreads();
  const float M = fmaxf(fmaxf(red[0], red[1]), fmaxf(red[2], red[3]));
  float e = (tid < vb) ? __expf(v.x - M) : 0.f;
  if (tid < NSC) wexp[tid] = e;
  float se = e * v.y;
  se += __shfl_xor(se, 32); se += __shfl_xor(se, 16); se += __shfl_xor(se, 8);
  se += __shfl_xor(se, 4);  se += __shfl_xor(se, 2);  se += __shfl_xor(se, 1);
  __syncthreads();
  if ((tid & 63) == 0) red[tid >> 6] = se;
  __syncthreads();
  const float S = red[0] + red[1] + red[2] + red[3];

  const int d = tid & 127;
  const int h = tid >> 7;
  const int i0 = h * 64;
  const int i1 = min(vb, i0 + 64);
  const float* ap = accbuf + ((size_t)b * NSC + i0) * D_ + d;
  float sum = 0.f;
  for (int i = i0; i < i1; ++i) sum += wexp[i] * ap[(size_t)(i - i0) * D_];
  if (h == 1) halfsum[d] = sum;
  __syncthreads();
  if (h == 0) {
    float rr = sum + ((vb > 64) ? halfsum[d] : 0.f);
    out[b * D_ + d] = ((S > 0.f) ? (rr / S) : 0.f) + bias[d];
  }
}

extern "C" void kernel_launch(void* const* d_in, const int* in_sizes, int n_in,
                              void* d_out, int out_size, void* d_ws, size_t ws_size,
                              hipStream_t stream) {
  const float* seq     = (const float*)d_in[0];
  const void*  len_raw = d_in[1];
  const float* key_w   = (const float*)d_in[2];
  const float* query_w = (const float*)d_in[3];
  const float* bias    = (const float*)d_in[4];
  float*       out     = (float*)d_out;

  uint16_t* wfrag  = (uint16_t*)d_ws;                          // 64 KB
  float2*   msbuf  = (float2*)((char*)d_ws + 65536);           // 64 KB
  float*    accbuf = (float*)((char*)d_ws + 131072);           // 4 MB
  int*      lens   = (int*)((char*)d_ws + 131072 + 4194304);   // 256 B

  prep<<<dim3(17), dim3(256), 0, stream>>>(key_w, query_w, len_raw, wfrag, lens);
  attn_partial<<<dim3(NXB, B_), dim3(256), 0, stream>>>(seq, lens, wfrag, msbuf, accbuf);
  attn_combine<<<dim3(B_), dim3(256), 0, stream>>>(msbuf, accbuf, lens, bias, out);
}